// Round 1
// baseline (475.678 us; speedup 1.0000x reference)
//
#include <hip/hip_runtime.h>

#define D 64
#define K 1024
#define NTOK (32 * 4096)       // 131072 tokens
#define TPB 256                 // threads per block, 1 token per thread
#define TILE 16                 // codes per inner tile

// d_out layout (all f32): quantized [NTOK*D] | one-hot [NTOK*K] | indices [NTOK]
#define Q_ELEMS ((size_t)NTOK * D)
#define OH_ELEMS ((size_t)NTOK * K)

__global__ __launch_bounds__(TPB, 2) void vq_kernel(
    const float* __restrict__ X,   // [NTOK, D]
    const float* __restrict__ E,   // [D, K]
    float* __restrict__ qout,      // [NTOK, D]
    float* __restrict__ oneh,      // [NTOK, K]
    float* __restrict__ idxout)    // [NTOK]
{
    __shared__ float e2s[K];
    __shared__ int   idxs[TPB];

    const int tid = threadIdx.x;
    const int tok = blockIdx.x * TPB + tid;

    // --- per-block ||e_k||^2 into LDS (coalesced: lanes read consecutive k) ---
    for (int k = tid; k < K; k += TPB) {
        float s = 0.f;
        #pragma unroll
        for (int d = 0; d < D; ++d) {
            float v = E[d * K + k];
            s = fmaf(v, v, s);
        }
        e2s[k] = s;
    }
    __syncthreads();

    // --- load this thread's token into registers (16 x float4) ---
    float x[D];
    {
        const float* xp = X + (size_t)tok * D;
        #pragma unroll
        for (int j = 0; j < D / 4; ++j) {
            float4 v = *reinterpret_cast<const float4*>(xp + 4 * j);
            x[4 * j + 0] = v.x; x[4 * j + 1] = v.y;
            x[4 * j + 2] = v.z; x[4 * j + 3] = v.w;
        }
    }

    // --- argmin over codes: dist_k = e2[k] - 2 * x.e_k  (||x||^2 constant) ---
    float best = 3.4e38f;
    int   bidx = 0;
    for (int t0 = 0; t0 < K; t0 += TILE) {
        float acc[TILE];
        #pragma unroll
        for (int j = 0; j < TILE; ++j) acc[j] = 0.f;

        // uniform addresses -> scalar loads; d fully unrolled so x[d] stays in VGPRs
        #pragma unroll
        for (int d = 0; d < D; ++d) {
            const float* ep = E + d * K + t0;
            #pragma unroll
            for (int j = 0; j < TILE; ++j)
                acc[j] = fmaf(x[d], ep[j], acc[j]);
        }

        #pragma unroll
        for (int j = 0; j < TILE; ++j) {
            float dist = fmaf(-2.f, acc[j], e2s[t0 + j]);
            if (dist < best) { best = dist; bidx = t0 + j; }
        }
    }

    idxs[tid] = bidx;

    // --- gather quantized column E[:, bidx]; write q_st = x + (q - x) ---
    {
        float q[D];
        const float* ec = E + bidx;
        #pragma unroll
        for (int d = 0; d < D; ++d) q[d] = ec[d * K];

        float* qp = qout + (size_t)tok * D;
        #pragma unroll
        for (int j = 0; j < D / 4; ++j) {
            float4 v;
            v.x = x[4 * j + 0] + (q[4 * j + 0] - x[4 * j + 0]);
            v.y = x[4 * j + 1] + (q[4 * j + 1] - x[4 * j + 1]);
            v.z = x[4 * j + 2] + (q[4 * j + 2] - x[4 * j + 2]);
            v.w = x[4 * j + 3] + (q[4 * j + 3] - x[4 * j + 3]);
            *reinterpret_cast<float4*>(qp + 4 * j) = v;
        }
    }

    // --- indices (as float, whole d_out is read as f32) ---
    idxout[tok] = (float)bidx;

    __syncthreads();  // idxs[] visible to whole block

    // --- one-hot rows for this block's 256 tokens: coalesced float4 stores ---
    {
        float4* base = reinterpret_cast<float4*>(oneh + (size_t)blockIdx.x * TPB * K);
        const int total = TPB * K / 4;  // 65536 float4 per block
        for (int i = tid; i < total; i += TPB) {
            int row = i >> 8;            // K/4 = 256 float4 per row
            int c4  = (i & 255) * 4;
            int id  = idxs[row];
            float4 v;
            v.x = (id == c4 + 0) ? 1.f : 0.f;
            v.y = (id == c4 + 1) ? 1.f : 0.f;
            v.z = (id == c4 + 2) ? 1.f : 0.f;
            v.w = (id == c4 + 3) ? 1.f : 0.f;
            base[i] = v;
        }
    }
}

extern "C" void kernel_launch(void* const* d_in, const int* in_sizes, int n_in,
                              void* d_out, int out_size, void* d_ws, size_t ws_size,
                              hipStream_t stream) {
    const float* X = (const float*)d_in[0];   // [32,4096,64]
    const float* E = (const float*)d_in[1];   // [64,1024]

    float* qout   = (float*)d_out;
    float* oneh   = qout + Q_ELEMS;
    float* idxout = oneh + OH_ELEMS;

    const int grid = NTOK / TPB;  // 512 blocks
    vq_kernel<<<grid, TPB, 0, stream>>>(X, E, qout, oneh, idxout);
}